// Round 1
// baseline (2385.833 us; speedup 1.0000x reference)
//
#include <hip/hip_runtime.h>
#include <hip/hip_bf16.h>
#include <math.h>

// Problem: B=16, L=4096, E=512, H=8, D=64, k_top=16.
// Pipeline (all fused/restructured):
//   Wc = Wo@Wv, bc = Wo@bv+bo                  (combine_kernel)
//   Qt = (queries@Wq^T+bq)^T per b  (B,E,L)    (gemm_kernel<true>)
//   Kt = (keys@Wk^T+bk)^T   per b -> d_out     (gemm_kernel<true>)
//   S(b,f) = sum_c Qf*conj(Kf)   via packed z=Q+iK Stockham FFT (fft_corr_kernel)
//   corr_mean(b,tau) = irfft(S)/(E*L)          (ifft_kernel)
//   top-18 + ambiguity flag                    (topk_kernel)
//   fp64 exact re-eval of flagged candidates   (refine_kernel)
//   top-16 + softmax -> probs/delays           (probs_kernel)
//   OV = values@Wc^T+bc  (reuses Qt buffer)    (gemm_kernel<false>)
//   out[b,l,:] = sum_i p_i * OV[b,(l+d_i)%L,:] (agg_kernel)
// Workspace peak ~136.1 MB.

#define B_ 16
#define L_ 4096
#define E_ 512
#define NCAND 18
#define KTOP 16

__device__ __forceinline__ float2 cmul(float2 a, float2 b) {
  return make_float2(a.x*b.x - a.y*b.y, a.x*b.y + a.y*b.x);
}

// ---------------- GEMM: Y = X @ W^T + bias ----------------
// X: (65536, 512) row-major. W: (512,512) [n][k]. TR=false: Y (65536,512).
// TR=true: Y transposed per batch: Y[(b*512+n)*4096 + l], m = b*4096+l.
template<bool TR>
__global__ __launch_bounds__(256) void gemm_kernel(
    const float* __restrict__ X, const float* __restrict__ W,
    const float* __restrict__ bias, float* __restrict__ Y)
{
  __shared__ float Xs[32][132];
  __shared__ float Ws[32][68];
  const int bn = blockIdx.x;   // 0..7   (fast dim -> same X tile shares L2)
  const int bm = blockIdx.y;   // 0..511
  const int tid = threadIdx.x;
  const int tm = tid & 15;
  const int tn = tid >> 4;

  float acc[8][4];
#pragma unroll
  for (int i = 0; i < 8; ++i)
#pragma unroll
    for (int j = 0; j < 4; ++j) acc[i][j] = 0.f;

  const float* Xbase = X + (size_t)bm * 128 * 512;
  const float* Wbase = W + (size_t)bn * 64 * 512;

  for (int k0 = 0; k0 < 512; k0 += 32) {
#pragma unroll
    for (int j = 0; j < 4; ++j) {
      int idx = tid + 256 * j;
      int r = idx >> 3;
      int c4 = (idx & 7) << 2;
      float4 v = *reinterpret_cast<const float4*>(Xbase + (size_t)r * 512 + k0 + c4);
      Xs[c4+0][r] = v.x; Xs[c4+1][r] = v.y; Xs[c4+2][r] = v.z; Xs[c4+3][r] = v.w;
    }
#pragma unroll
    for (int j = 0; j < 2; ++j) {
      int idx = tid + 256 * j;
      int r = idx >> 3;
      int c4 = (idx & 7) << 2;
      float4 v = *reinterpret_cast<const float4*>(Wbase + (size_t)r * 512 + k0 + c4);
      Ws[c4+0][r] = v.x; Ws[c4+1][r] = v.y; Ws[c4+2][r] = v.z; Ws[c4+3][r] = v.w;
    }
    __syncthreads();
#pragma unroll
    for (int kk = 0; kk < 32; ++kk) {
      float4 a0 = *reinterpret_cast<const float4*>(&Xs[kk][tm*4]);
      float4 a1 = *reinterpret_cast<const float4*>(&Xs[kk][tm*4 + 64]);
      float4 b0 = *reinterpret_cast<const float4*>(&Ws[kk][tn*4]);
      float a[8] = {a0.x,a0.y,a0.z,a0.w,a1.x,a1.y,a1.z,a1.w};
      float bb[4] = {b0.x,b0.y,b0.z,b0.w};
#pragma unroll
      for (int i = 0; i < 8; ++i)
#pragma unroll
        for (int j = 0; j < 4; ++j) acc[i][j] += a[i]*bb[j];
    }
    __syncthreads();
  }

  if (TR) {
    int m0 = bm*128 + tm*4;       // rows for acc[0..3]; acc[4..7] at +64
    int b  = m0 >> 12;
    int l0 = m0 & 4095;
#pragma unroll
    for (int j = 0; j < 4; ++j) {
      int n = bn*64 + tn*4 + j;
      float bs = bias[n];
      float4 v0 = make_float4(acc[0][j]+bs, acc[1][j]+bs, acc[2][j]+bs, acc[3][j]+bs);
      float4 v1 = make_float4(acc[4][j]+bs, acc[5][j]+bs, acc[6][j]+bs, acc[7][j]+bs);
      float* dst = Y + ((size_t)b*512 + n) * 4096;
      *reinterpret_cast<float4*>(dst + l0)      = v0;
      *reinterpret_cast<float4*>(dst + l0 + 64) = v1;
    }
  } else {
    int n0 = bn*64 + tn*4;
    float4 bs = *reinterpret_cast<const float4*>(bias + n0);
#pragma unroll
    for (int i = 0; i < 8; ++i) {
      int m = bm*128 + tm*4 + (i & 3) + ((i >> 2) * 64);
      float4 v = make_float4(acc[i][0]+bs.x, acc[i][1]+bs.y, acc[i][2]+bs.z, acc[i][3]+bs.w);
      *reinterpret_cast<float4*>(Y + (size_t)m*512 + n0) = v;
    }
  }
}

// ---------------- combine: Wc = Wo@Wv, bc = Wo@bv + bo ----------------
__global__ __launch_bounds__(256) void combine_kernel(
    const float* __restrict__ Wo, const float* __restrict__ Wv,
    const float* __restrict__ bv, const float* __restrict__ bo,
    float* __restrict__ Wc, float* __restrict__ bc)
{
  int n = blockIdx.x;
  int tid = threadIdx.x;
  float a0 = 0.f, a1 = 0.f;
  for (int j = 0; j < 512; ++j) {
    float wo = Wo[(size_t)n*512 + j];
    a0 += wo * Wv[(size_t)j*512 + tid];
    a1 += wo * Wv[(size_t)j*512 + tid + 256];
  }
  Wc[(size_t)n*512 + tid]       = a0;
  Wc[(size_t)n*512 + tid + 256] = a1;

  float p = 0.f;
  for (int j = tid; j < 512; j += 256) p += Wo[(size_t)n*512 + j] * bv[j];
  __shared__ float red[256];
  red[tid] = p; __syncthreads();
  for (int off = 128; off > 0; off >>= 1) {
    if (tid < off) red[tid] += red[tid + off];
    __syncthreads();
  }
  if (tid == 0) bc[n] = red[0] + bo[n];
}

// ---------------- twiddle table: tw[k] = e^{-2pi i k/4096}, k<2048 ----------------
__global__ void init_tw_kernel(float2* __restrict__ tw) {
  int k = blockIdx.x * 256 + threadIdx.x;
  if (k < 2048) {
    double ang = -2.0 * M_PI * (double)k / 4096.0;
    tw[k] = make_float2((float)cos(ang), (float)sin(ang));
  }
}

__global__ void zero_kernel(float* __restrict__ p, int n) {
  int i = blockIdx.x * 256 + threadIdx.x;
  if (i < n) p[i] = 0.f;
}

// ---------------- packed FFT + spectrum accumulate ----------------
// block = (b, group g of 16 channels). z = Q + iK, Stockham DIF, natural in/out.
__global__ __launch_bounds__(256) void fft_corr_kernel(
    const float* __restrict__ Qt, const float* __restrict__ Kt,
    const float2* __restrict__ tw, float* __restrict__ S)
{
  __shared__ float2 buf[2][4096];   // 64 KB
  const int b = blockIdx.x >> 5;
  const int g = blockIdx.x & 31;
  const int tid = threadIdx.x;

  float2 acc[16];
#pragma unroll
  for (int r = 0; r < 16; ++r) acc[r] = make_float2(0.f, 0.f);

  for (int cc = 0; cc < 16; ++cc) {
    const int c = g*16 + cc;
    const float* Qr = Qt + ((size_t)b*512 + c) * 4096;
    const float* Kr = Kt + ((size_t)b*512 + c) * 4096;
#pragma unroll
    for (int r = 0; r < 4; ++r) {
      int l = (tid + 256*r) * 4;
      float4 q4 = *reinterpret_cast<const float4*>(Qr + l);
      float4 k4 = *reinterpret_cast<const float4*>(Kr + l);
      buf[0][l+0] = make_float2(q4.x, k4.x);
      buf[0][l+1] = make_float2(q4.y, k4.y);
      buf[0][l+2] = make_float2(q4.z, k4.z);
      buf[0][l+3] = make_float2(q4.w, k4.w);
    }
    __syncthreads();

    int cur = 0, n = 4096, s = 1;
    for (int st = 0; st < 12; ++st) {
      int m = n >> 1;
      const float2* src = buf[cur];
      float2* dst = buf[cur ^ 1];
#pragma unroll
      for (int r = 0; r < 8; ++r) {
        int idx = tid + 256*r;
        int q = idx & (s - 1);
        int p = idx >> st;
        float2 w = tw[p << st];          // e^{-2pi i p/n}
        float2 a  = src[q + s*p];
        float2 bv = src[q + s*(p + m)];
        float2 dif = make_float2(a.x - bv.x, a.y - bv.y);
        dst[q + 2*s*p]     = make_float2(a.x + bv.x, a.y + bv.y);
        dst[q + 2*s*p + s] = cmul(dif, w);
      }
      __syncthreads();
      cur ^= 1; n >>= 1; s <<= 1;
    }
    // Z in buf[0] (12 swaps -> back to 0), natural order. Extract Qf*conj(Kf).
#pragma unroll
    for (int r = 0; r < 16; ++r) {
      int f = tid + 256*r;
      float2 zf = buf[0][f];
      float2 zm = buf[0][(4096 - f) & 4095];
      float2 qf = make_float2(0.5f*(zf.x + zm.x), 0.5f*(zf.y - zm.y));
      float2 df = make_float2(0.5f*(zf.x - zm.x), 0.5f*(zf.y + zm.y));
      float2 kf = make_float2(df.y, -df.x);     // -i * df
      acc[r].x += qf.x*kf.x + qf.y*kf.y;        // qf * conj(kf)
      acc[r].y += qf.y*kf.x - qf.x*kf.y;
    }
    __syncthreads();
  }
#pragma unroll
  for (int r = 0; r < 16; ++r) {
    int f = tid + 256*r;
    atomicAdd(&S[(size_t)(b*4096 + f)*2 + 0], acc[r].x);
    atomicAdd(&S[(size_t)(b*4096 + f)*2 + 1], acc[r].y);
  }
}

// ---------------- inverse FFT per batch -> corr_mean ----------------
__global__ __launch_bounds__(256) void ifft_kernel(
    const float* __restrict__ S, const float2* __restrict__ tw,
    float* __restrict__ corr)
{
  __shared__ float2 buf[2][4096];
  const int b = blockIdx.x;
  const int tid = threadIdx.x;
  const float2* Sc = reinterpret_cast<const float2*>(S) + (size_t)b * 4096;
#pragma unroll
  for (int r = 0; r < 16; ++r) {
    int f = tid + 256*r;
    buf[0][f] = Sc[f];
  }
  __syncthreads();
  int cur = 0, n = 4096, s = 1;
  for (int st = 0; st < 12; ++st) {
    int m = n >> 1;
    const float2* src = buf[cur];
    float2* dst = buf[cur ^ 1];
#pragma unroll
    for (int r = 0; r < 8; ++r) {
      int idx = tid + 256*r;
      int q = idx & (s - 1);
      int p = idx >> st;
      float2 w = tw[p << st];
      w.y = -w.y;                         // conj -> e^{+2pi i p/n}
      float2 a  = src[q + s*p];
      float2 bv = src[q + s*(p + m)];
      float2 dif = make_float2(a.x - bv.x, a.y - bv.y);
      dst[q + 2*s*p]     = make_float2(a.x + bv.x, a.y + bv.y);
      dst[q + 2*s*p + s] = cmul(dif, w);
    }
    __syncthreads();
    cur ^= 1; n >>= 1; s <<= 1;
  }
  const float scale = 1.0f / (512.0f * 4096.0f);   // 1/(E*L)
#pragma unroll
  for (int r = 0; r < 16; ++r) {
    int t = tid + 256*r;
    corr[(size_t)b*4096 + t] = buf[0][t].x * scale;
  }
}

// ---------------- top-18 per batch + ambiguity flag ----------------
__global__ __launch_bounds__(256) void topk_kernel(
    const float* __restrict__ corr, float* __restrict__ cand_val,
    int* __restrict__ cand_idx, int* __restrict__ flags)
{
  __shared__ float vals[4096];
  __shared__ float rv[256];
  __shared__ int   ri[256];
  const int b = blockIdx.x;
  const int tid = threadIdx.x;
#pragma unroll
  for (int r = 0; r < 16; ++r) vals[tid + 256*r] = corr[(size_t)b*4096 + tid + 256*r];
  __syncthreads();

  for (int it = 0; it < NCAND; ++it) {
    float best = -1e30f; int bi = -1;
#pragma unroll
    for (int r = 0; r < 16; ++r) {
      int i = tid + 256*r;
      float v = vals[i];
      if (v > best) { best = v; bi = i; }
    }
    rv[tid] = best; ri[tid] = bi;
    __syncthreads();
    for (int off = 128; off > 0; off >>= 1) {
      if (tid < off) {
        float v2 = rv[tid + off]; int i2 = ri[tid + off];
        if (v2 > rv[tid] || (v2 == rv[tid] && i2 < ri[tid])) { rv[tid] = v2; ri[tid] = i2; }
      }
      __syncthreads();
    }
    if (tid == 0) {
      cand_val[b*NCAND + it] = rv[0];
      cand_idx[b*NCAND + it] = ri[0];
      vals[ri[0]] = -1e30f;
    }
    __syncthreads();
  }
  if (tid == 0)
    flags[b] = (cand_val[b*NCAND + 15] - cand_val[b*NCAND + 16] < 0.02f) ? 1 : 0;
}

// ---------------- fp64 exact refinement of flagged candidates ----------------
__global__ __launch_bounds__(256) void refine_kernel(
    const float* __restrict__ Qt, const float* __restrict__ Kt,
    const int* __restrict__ cand_idx, const int* __restrict__ flags,
    float* __restrict__ cand_val)
{
  const int b  = blockIdx.x / NCAND;
  const int ci = blockIdx.x % NCAND;
  if (!flags[b]) return;
  const int tau = cand_idx[b*NCAND + ci];
  const int tid = threadIdx.x;
  const float* Qb = Qt + (size_t)b * 512 * 4096;
  const float* Kb = Kt + (size_t)b * 512 * 4096;
  double acc = 0.0;
  for (int c = 0; c < 512; ++c) {
    const float* Qc = Qb + (size_t)c * 4096;
    const float* Kc = Kb + (size_t)c * 4096;
    for (int j = 0; j < 16; ++j) {
      int l = tid + 256*j;
      int lt = (l + tau) & 4095;
      acc += (double)Qc[lt] * (double)Kc[l];
    }
  }
  __shared__ double red[256];
  red[tid] = acc; __syncthreads();
  for (int off = 128; off > 0; off >>= 1) {
    if (tid < off) red[tid] += red[tid + off];
    __syncthreads();
  }
  if (tid == 0) cand_val[b*NCAND + ci] = (float)(red[0] / 512.0);
}

// ---------------- select top-16 of 18, softmax ----------------
__global__ void probs_kernel(const float* __restrict__ cand_val,
                             const int* __restrict__ cand_idx,
                             float* __restrict__ probs, int* __restrict__ delays)
{
  int b = blockIdx.x;
  if (threadIdx.x != 0) return;
  float v[NCAND]; int ix[NCAND]; bool used[NCAND];
  for (int i = 0; i < NCAND; ++i) {
    v[i] = cand_val[b*NCAND + i]; ix[i] = cand_idx[b*NCAND + i]; used[i] = false;
  }
  float sel_v[KTOP]; int sel_i[KTOP];
  for (int k = 0; k < KTOP; ++k) {
    int best = -1;
    for (int i = 0; i < NCAND; ++i) {
      if (used[i]) continue;
      if (best < 0 || v[i] > v[best] || (v[i] == v[best] && ix[i] < ix[best])) best = i;
    }
    used[best] = true; sel_v[k] = v[best]; sel_i[k] = ix[best];
  }
  float mx = sel_v[0];
  for (int k = 1; k < KTOP; ++k) mx = fmaxf(mx, sel_v[k]);
  float e[KTOP]; float se = 0.f;
  for (int k = 0; k < KTOP; ++k) { e[k] = __expf(sel_v[k] - mx); se += e[k]; }
  for (int k = 0; k < KTOP; ++k) {
    probs[b*KTOP + k]  = e[k] / se;
    delays[b*KTOP + k] = sel_i[k];
  }
}

// ---------------- shift-aggregate: out[b,l,:] = sum_i p_i OV[b,(l+d_i)%L,:] ----------------
__global__ __launch_bounds__(256) void agg_kernel(
    const float* __restrict__ OV, const float* __restrict__ probs,
    const int* __restrict__ delays, float* __restrict__ out)
{
  int row = blockIdx.x * 2 + (threadIdx.x >> 7);   // global row in [0, B*L)
  int b = row >> 12;
  int l = row & 4095;
  int c4 = (threadIdx.x & 127) << 2;
  float p[KTOP]; int d[KTOP];
#pragma unroll
  for (int i = 0; i < KTOP; ++i) { p[i] = probs[b*KTOP + i]; d[i] = delays[b*KTOP + i]; }
  float4 acc = make_float4(0.f, 0.f, 0.f, 0.f);
#pragma unroll
  for (int i = 0; i < KTOP; ++i) {
    int ls = (l + d[i]) & 4095;
    float4 v = *reinterpret_cast<const float4*>(OV + ((size_t)(b*4096 + ls))*512 + c4);
    acc.x += p[i]*v.x; acc.y += p[i]*v.y; acc.z += p[i]*v.z; acc.w += p[i]*v.w;
  }
  *reinterpret_cast<float4*>(out + (size_t)row*512 + c4) = acc;
}

// ---------------- launch ----------------
extern "C" void kernel_launch(void* const* d_in, const int* in_sizes, int n_in,
                              void* d_out, int out_size, void* d_ws, size_t ws_size,
                              hipStream_t stream)
{
  const float* queries = (const float*)d_in[0];
  const float* keys    = (const float*)d_in[1];
  const float* values  = (const float*)d_in[2];
  const float* Wq = (const float*)d_in[3];
  const float* bq = (const float*)d_in[4];
  const float* Wk = (const float*)d_in[5];
  const float* bk = (const float*)d_in[6];
  const float* Wv = (const float*)d_in[7];
  const float* bv = (const float*)d_in[8];
  const float* Wo = (const float*)d_in[9];
  const float* bo = (const float*)d_in[10];

  char* ws = (char*)d_ws;
  size_t off = 0;
  float* Qt = (float*)(ws + off);     off += (size_t)B_*E_*L_*4;   // 134,217,728
  float* S  = (float*)(ws + off);     off += (size_t)B_*L_*2*4;    // 524,288
  float* corr = (float*)(ws + off);   off += (size_t)B_*L_*4;      // 262,144
  float* Wc = (float*)(ws + off);     off += (size_t)E_*E_*4;      // 1,048,576
  float* bc = (float*)(ws + off);     off += (size_t)E_*4;
  float2* tw = (float2*)(ws + off);   off += (size_t)2048*8;
  float* cand_val = (float*)(ws + off); off += (size_t)B_*NCAND*4;
  int*   cand_idx = (int*)(ws + off);   off += (size_t)B_*NCAND*4;
  int*   flags    = (int*)(ws + off);   off += (size_t)B_*4;
  float* probs    = (float*)(ws + off); off += (size_t)B_*KTOP*4;
  int*   delays   = (int*)(ws + off);   off += (size_t)B_*KTOP*4;
  // peak ws use ~136.1 MB

  float* Kt = (float*)d_out;   // d_out doubles as K scratch until agg_kernel
  float* OV = Qt;              // OV reuses Q buffer after FFT + refinement

  init_tw_kernel<<<8, 256, 0, stream>>>(tw);
  zero_kernel<<<(B_*L_*2 + 255)/256, 256, 0, stream>>>(S, B_*L_*2);
  combine_kernel<<<E_, 256, 0, stream>>>(Wo, Wv, bv, bo, Wc, bc);
  gemm_kernel<true><<<dim3(8, 512), 256, 0, stream>>>(queries, Wq, bq, Qt);
  gemm_kernel<true><<<dim3(8, 512), 256, 0, stream>>>(keys,    Wk, bk, Kt);
  fft_corr_kernel<<<B_*32, 256, 0, stream>>>(Qt, Kt, tw, S);
  ifft_kernel<<<B_, 256, 0, stream>>>(S, tw, corr);
  topk_kernel<<<B_, 256, 0, stream>>>(corr, cand_val, cand_idx, flags);
  refine_kernel<<<B_*NCAND, 256, 0, stream>>>(Qt, Kt, cand_idx, flags, cand_val);
  probs_kernel<<<B_, 64, 0, stream>>>(cand_val, cand_idx, probs, delays);
  gemm_kernel<false><<<dim3(8, 512), 256, 0, stream>>>(values, Wc, bc, OV);
  agg_kernel<<<B_*L_/2, 256, 0, stream>>>(OV, probs, delays, (float*)d_out);
}

// Round 2
// 1200.375 us; speedup vs baseline: 1.9876x; 1.9876x over previous
//
#include <hip/hip_runtime.h>
#include <hip/hip_bf16.h>
#include <math.h>

// B=16, L=4096, E=512, H=8, D=64, k_top=16.
// Pipeline:
//   Wc = Wo@Wv, bc = Wo@bv+bo                    (combine_kernel)
//   Qt = (queries@Wq^T+bq)^T per b  (B,E,L)      (gemm_mfma<true>, split-bf16 MFMA)
//   Kt = (keys@Wk^T+bk)^T -> d_out               (gemm_mfma<true>)
//   Spart(b,g,f) = sum_{c in g} Qf*conj(Kf)      (fft_corr_kernel, packed z=Q+iK)
//   corr_mean = irfft(sum_g Spart)/(E*L)         (ifft_kernel, deterministic sum)
//   top-18 + ambiguity flag                      (topk_kernel)
//   exact re-eval of flagged batches (read-once) (refine_kernel + finalize_kernel)
//   top-16 + softmax                             (probs_kernel)
//   OV = values@Wc^T+bc  (reuses Qt)             (gemm_mfma<false>)
//   out[b,l,:] = sum_i p_i OV[b,(l+d_i)%L,:]     (agg_kernel)

#define B_ 16
#define L_ 4096
#define E_ 512
#define NCAND 18
#define KTOP 16

typedef __attribute__((ext_vector_type(8))) short bf16x8;
typedef __attribute__((ext_vector_type(4))) float f32x4;

__device__ __forceinline__ float2 cmul(float2 a, float2 b) {
  return make_float2(a.x*b.x - a.y*b.y, a.x*b.y + a.y*b.x);
}
__device__ __forceinline__ unsigned short bf16_rne(float x) {
  unsigned int u = __float_as_uint(x);
  unsigned int r = u + 0x7FFFu + ((u >> 16) & 1u);
  return (unsigned short)(r >> 16);
}
__device__ __forceinline__ float bf16_f(unsigned short h) {
  return __uint_as_float(((unsigned int)h) << 16);
}

// ---------------- MFMA split-bf16 GEMM ----------------
// X: (65536,512) rows over k. W: (512,512) rows over k.
// TR=false: Y[m][n] = X[m]·W[n] + bias[n], Y (65536,512).
// TR=true : Y[(b*512+n)*4096 + l] = X[m=(b,l)]·W[n] + bias[n]  (transposed per batch)
// Tile: 128 X-rows (blockIdx.x) × 128 W-rows (blockIdx.y), BK=32, 4 waves (2×2),
// each wave 64×64 = 4×4 frags of 16x16x32. A-operand = (TR? W : X), B = other.
template<bool TR>
__global__ __launch_bounds__(256) void gemm_mfma(
    const float* __restrict__ X, const float* __restrict__ W,
    const float* __restrict__ bias, float* __restrict__ Y)
{
  __shared__ unsigned short Xhi[4*128*8], Xlo[4*128*8];
  __shared__ unsigned short Whi[4*128*8], Wlo[4*128*8];
  const int tid  = threadIdx.x;
  const int bx   = blockIdx.x;            // X-row tile (0..511)
  const int by   = blockIdx.y;            // W-row tile (0..3)
  const int wave = tid >> 6;
  const int lane = tid & 63;
  const int lr   = lane & 15;             // row-in-frag (A/B), col of D
  const int lk   = lane >> 4;             // k-octet; D row group
  const int wr   = wave >> 1, wc = wave & 1;

  f32x4 acc[4][4];
#pragma unroll
  for (int i = 0; i < 4; ++i)
#pragma unroll
    for (int j = 0; j < 4; ++j) acc[i][j] = (f32x4){0.f, 0.f, 0.f, 0.f};

  const float* Xb = X + (size_t)bx * 128 * 512;
  const float* Wb = W + (size_t)by * 128 * 512;

  for (int k0 = 0; k0 < 512; k0 += 32) {
    // ---- stage + split fp32 -> bf16 hi/lo ----
#pragma unroll
    for (int q = 0; q < 4; ++q) {
      int f  = tid + 256*q;          // 0..1023
      int r  = f >> 3;               // row 0..127
      int kq = (f & 7) << 2;         // k offset 0..28 step 4
      int off = ((kq >> 3)*128 + r)*8 + (kq & 7);
      float4 xv = *reinterpret_cast<const float4*>(Xb + (size_t)r*512 + k0 + kq);
      float4 wv = *reinterpret_cast<const float4*>(Wb + (size_t)r*512 + k0 + kq);
      float xa[4] = {xv.x, xv.y, xv.z, xv.w};
      float wa[4] = {wv.x, wv.y, wv.z, wv.w};
      unsigned int xh[2], xl[2], wh[2], wl[2];
#pragma unroll
      for (int p = 0; p < 2; ++p) {
        unsigned short h0 = bf16_rne(xa[2*p]),   h1 = bf16_rne(xa[2*p+1]);
        unsigned short l0 = bf16_rne(xa[2*p]   - bf16_f(h0));
        unsigned short l1 = bf16_rne(xa[2*p+1] - bf16_f(h1));
        xh[p] = (unsigned int)h0 | ((unsigned int)h1 << 16);
        xl[p] = (unsigned int)l0 | ((unsigned int)l1 << 16);
        unsigned short g0 = bf16_rne(wa[2*p]),   g1 = bf16_rne(wa[2*p+1]);
        unsigned short m0 = bf16_rne(wa[2*p]   - bf16_f(g0));
        unsigned short m1 = bf16_rne(wa[2*p+1] - bf16_f(g1));
        wh[p] = (unsigned int)g0 | ((unsigned int)g1 << 16);
        wl[p] = (unsigned int)m0 | ((unsigned int)m1 << 16);
      }
      *reinterpret_cast<uint2*>(&Xhi[off]) = make_uint2(xh[0], xh[1]);
      *reinterpret_cast<uint2*>(&Xlo[off]) = make_uint2(xl[0], xl[1]);
      *reinterpret_cast<uint2*>(&Whi[off]) = make_uint2(wh[0], wh[1]);
      *reinterpret_cast<uint2*>(&Wlo[off]) = make_uint2(wl[0], wl[1]);
    }
    __syncthreads();

    const unsigned short* Ahi = TR ? Whi : Xhi;
    const unsigned short* Alo = TR ? Wlo : Xlo;
    const unsigned short* Bhi = TR ? Xhi : Whi;
    const unsigned short* Blo = TR ? Xlo : Wlo;

    bf16x8 ah[4], al[4], bh[4], bl[4];
#pragma unroll
    for (int i = 0; i < 4; ++i) {
      int oa = (lk*128 + (wr*64 + i*16 + lr))*8;
      int ob = (lk*128 + (wc*64 + i*16 + lr))*8;
      ah[i] = *reinterpret_cast<const bf16x8*>(&Ahi[oa]);
      al[i] = *reinterpret_cast<const bf16x8*>(&Alo[oa]);
      bh[i] = *reinterpret_cast<const bf16x8*>(&Bhi[ob]);
      bl[i] = *reinterpret_cast<const bf16x8*>(&Blo[ob]);
    }
#pragma unroll
    for (int fr = 0; fr < 4; ++fr)
#pragma unroll
      for (int fc = 0; fc < 4; ++fc) {
        acc[fr][fc] = __builtin_amdgcn_mfma_f32_16x16x32_bf16(ah[fr], bh[fc], acc[fr][fc], 0, 0, 0);
        acc[fr][fc] = __builtin_amdgcn_mfma_f32_16x16x32_bf16(ah[fr], bl[fc], acc[fr][fc], 0, 0, 0);
        acc[fr][fc] = __builtin_amdgcn_mfma_f32_16x16x32_bf16(al[fr], bh[fc], acc[fr][fc], 0, 0, 0);
      }
    __syncthreads();
  }

  // ---- epilogue: D[row = A-dim: (lk*4+r)][col = B-dim: lr] ----
#pragma unroll
  for (int fr = 0; fr < 4; ++fr) {
#pragma unroll
    for (int fc = 0; fc < 4; ++fc) {
      int ar0 = (TR ? by*128 : bx*128) + wr*64 + fr*16 + lk*4;  // A-dim base
      int bc  = (TR ? bx*128 : by*128) + wc*64 + fc*16 + lr;    // B-dim
      if (TR) {
        int bb = bc >> 12, lpos = bc & 4095;
#pragma unroll
        for (int r = 0; r < 4; ++r) {
          int n = ar0 + r;
          Y[((size_t)(bb*512 + n))*4096 + lpos] = acc[fr][fc][r] + bias[n];
        }
      } else {
        float bs = bias[bc];
#pragma unroll
        for (int r = 0; r < 4; ++r) {
          int m = ar0 + r;
          Y[(size_t)m*512 + bc] = acc[fr][fc][r] + bs;
        }
      }
    }
  }
}

// ---------------- combine: Wc = Wo@Wv, bc = Wo@bv + bo ----------------
__global__ __launch_bounds__(256) void combine_kernel(
    const float* __restrict__ Wo, const float* __restrict__ Wv,
    const float* __restrict__ bv, const float* __restrict__ bo,
    float* __restrict__ Wc, float* __restrict__ bc)
{
  int n = blockIdx.x;
  int tid = threadIdx.x;
  float a0 = 0.f, a1 = 0.f;
  for (int j = 0; j < 512; ++j) {
    float wo = Wo[(size_t)n*512 + j];
    a0 += wo * Wv[(size_t)j*512 + tid];
    a1 += wo * Wv[(size_t)j*512 + tid + 256];
  }
  Wc[(size_t)n*512 + tid]       = a0;
  Wc[(size_t)n*512 + tid + 256] = a1;

  float p = 0.f;
  for (int j = tid; j < 512; j += 256) p += Wo[(size_t)n*512 + j] * bv[j];
  __shared__ float red[256];
  red[tid] = p; __syncthreads();
  for (int off = 128; off > 0; off >>= 1) {
    if (tid < off) red[tid] += red[tid + off];
    __syncthreads();
  }
  if (tid == 0) bc[n] = red[0] + bo[n];
}

// ---------------- twiddles ----------------
__global__ void init_tw_kernel(float2* __restrict__ tw) {
  int k = blockIdx.x * 256 + threadIdx.x;
  if (k < 2048) {
    double ang = -2.0 * M_PI * (double)k / 4096.0;
    tw[k] = make_float2((float)cos(ang), (float)sin(ang));
  }
}

// ---------------- packed FFT -> per-group spectrum partials ----------------
__global__ __launch_bounds__(256) void fft_corr_kernel(
    const float* __restrict__ Qt, const float* __restrict__ Kt,
    const float2* __restrict__ tw, float2* __restrict__ Spart)
{
  __shared__ float2 buf[2][4096];
  const int b = blockIdx.x >> 5;
  const int g = blockIdx.x & 31;
  const int tid = threadIdx.x;

  float2 acc[16];
#pragma unroll
  for (int r = 0; r < 16; ++r) acc[r] = make_float2(0.f, 0.f);

  for (int cc = 0; cc < 16; ++cc) {
    const int c = g*16 + cc;
    const float* Qr = Qt + ((size_t)b*512 + c) * 4096;
    const float* Kr = Kt + ((size_t)b*512 + c) * 4096;
#pragma unroll
    for (int r = 0; r < 4; ++r) {
      int l = (tid + 256*r) * 4;
      float4 q4 = *reinterpret_cast<const float4*>(Qr + l);
      float4 k4 = *reinterpret_cast<const float4*>(Kr + l);
      buf[0][l+0] = make_float2(q4.x, k4.x);
      buf[0][l+1] = make_float2(q4.y, k4.y);
      buf[0][l+2] = make_float2(q4.z, k4.z);
      buf[0][l+3] = make_float2(q4.w, k4.w);
    }
    __syncthreads();

    int cur = 0, n = 4096, s = 1;
    for (int st = 0; st < 12; ++st) {
      int m = n >> 1;
      const float2* src = buf[cur];
      float2* dst = buf[cur ^ 1];
#pragma unroll
      for (int r = 0; r < 8; ++r) {
        int idx = tid + 256*r;
        int q = idx & (s - 1);
        int p = idx >> st;
        float2 w = tw[p << st];
        float2 a  = src[q + s*p];
        float2 bv = src[q + s*(p + m)];
        float2 dif = make_float2(a.x - bv.x, a.y - bv.y);
        dst[q + 2*s*p]     = make_float2(a.x + bv.x, a.y + bv.y);
        dst[q + 2*s*p + s] = cmul(dif, w);
      }
      __syncthreads();
      cur ^= 1; n >>= 1; s <<= 1;
    }
#pragma unroll
    for (int r = 0; r < 16; ++r) {
      int f = tid + 256*r;
      float2 zf = buf[0][f];
      float2 zm = buf[0][(4096 - f) & 4095];
      float2 qf = make_float2(0.5f*(zf.x + zm.x), 0.5f*(zf.y - zm.y));
      float2 df = make_float2(0.5f*(zf.x - zm.x), 0.5f*(zf.y + zm.y));
      float2 kf = make_float2(df.y, -df.x);
      acc[r].x += qf.x*kf.x + qf.y*kf.y;
      acc[r].y += qf.y*kf.x - qf.x*kf.y;
    }
    __syncthreads();
  }
  float2* Sp = Spart + ((size_t)(b*32 + g)) * 4096;
#pragma unroll
  for (int r = 0; r < 16; ++r) {
    int f = tid + 256*r;
    Sp[f] = acc[r];
  }
}

// ---------------- inverse FFT per batch -> corr_mean ----------------
__global__ __launch_bounds__(256) void ifft_kernel(
    const float2* __restrict__ Spart, const float2* __restrict__ tw,
    float* __restrict__ corr)
{
  __shared__ float2 buf[2][4096];
  const int b = blockIdx.x;
  const int tid = threadIdx.x;
#pragma unroll
  for (int r = 0; r < 16; ++r) {
    int f = tid + 256*r;
    float sx = 0.f, sy = 0.f;
    for (int g = 0; g < 32; ++g) {
      float2 v = Spart[((size_t)(b*32 + g))*4096 + f];
      sx += v.x; sy += v.y;
    }
    buf[0][f] = make_float2(sx, sy);
  }
  __syncthreads();
  int cur = 0, n = 4096, s = 1;
  for (int st = 0; st < 12; ++st) {
    int m = n >> 1;
    const float2* src = buf[cur];
    float2* dst = buf[cur ^ 1];
#pragma unroll
    for (int r = 0; r < 8; ++r) {
      int idx = tid + 256*r;
      int q = idx & (s - 1);
      int p = idx >> st;
      float2 w = tw[p << st];
      w.y = -w.y;
      float2 a  = src[q + s*p];
      float2 bv = src[q + s*(p + m)];
      float2 dif = make_float2(a.x - bv.x, a.y - bv.y);
      dst[q + 2*s*p]     = make_float2(a.x + bv.x, a.y + bv.y);
      dst[q + 2*s*p + s] = cmul(dif, w);
    }
    __syncthreads();
    cur ^= 1; n >>= 1; s <<= 1;
  }
  const float scale = 1.0f / (512.0f * 4096.0f);
#pragma unroll
  for (int r = 0; r < 16; ++r) {
    int t = tid + 256*r;
    corr[(size_t)b*4096 + t] = buf[0][t].x * scale;
  }
}

// ---------------- top-18 per batch + ambiguity flag ----------------
__global__ __launch_bounds__(256) void topk_kernel(
    const float* __restrict__ corr, float* __restrict__ cand_val,
    int* __restrict__ cand_idx, int* __restrict__ flags)
{
  __shared__ float vals[4096];
  __shared__ float rv[256];
  __shared__ int   ri[256];
  const int b = blockIdx.x;
  const int tid = threadIdx.x;
#pragma unroll
  for (int r = 0; r < 16; ++r) vals[tid + 256*r] = corr[(size_t)b*4096 + tid + 256*r];
  __syncthreads();

  for (int it = 0; it < NCAND; ++it) {
    float best = -1e30f; int bi = -1;
#pragma unroll
    for (int r = 0; r < 16; ++r) {
      int i = tid + 256*r;
      float v = vals[i];
      if (v > best) { best = v; bi = i; }
    }
    rv[tid] = best; ri[tid] = bi;
    __syncthreads();
    for (int off = 128; off > 0; off >>= 1) {
      if (tid < off) {
        float v2 = rv[tid + off]; int i2 = ri[tid + off];
        if (v2 > rv[tid] || (v2 == rv[tid] && i2 < ri[tid])) { rv[tid] = v2; ri[tid] = i2; }
      }
      __syncthreads();
    }
    if (tid == 0) {
      cand_val[b*NCAND + it] = rv[0];
      cand_idx[b*NCAND + it] = ri[0];
      vals[ri[0]] = -1e30f;
    }
    __syncthreads();
  }
  if (tid == 0)
    flags[b] = (cand_val[b*NCAND + 15] - cand_val[b*NCAND + 16] < 0.02f) ? 1 : 0;
}

// ---------------- exact refinement: read-once, all 18 taus ----------------
// grid: B*32 blocks; block = (b, channel chunk of 16). Writes per-chunk partials.
__global__ __launch_bounds__(256) void refine_kernel(
    const float* __restrict__ Qt, const float* __restrict__ Kt,
    const int* __restrict__ cand_idx, const int* __restrict__ flags,
    float* __restrict__ refpart)
{
  const int b = blockIdx.x >> 5;
  const int chunk = blockIdx.x & 31;
  if (!flags[b]) return;
  __shared__ float Qs[4096];
  __shared__ float red[4*NCAND];
  const int tid = threadIdx.x;
  int taus[NCAND];
#pragma unroll
  for (int i = 0; i < NCAND; ++i) taus[i] = cand_idx[b*NCAND + i];
  float acc[NCAND];
#pragma unroll
  for (int i = 0; i < NCAND; ++i) acc[i] = 0.f;

  for (int cc = 0; cc < 16; ++cc) {
    int c = chunk*16 + cc;
    const float* Qc = Qt + ((size_t)b*512 + c)*4096;
    const float* Kc = Kt + ((size_t)b*512 + c)*4096;
    __syncthreads();
#pragma unroll
    for (int rr = 0; rr < 4; ++rr) {
      int l4 = (tid + 256*rr)*4;
      *reinterpret_cast<float4*>(&Qs[l4]) = *reinterpret_cast<const float4*>(Qc + l4);
    }
    __syncthreads();
#pragma unroll 2
    for (int j = 0; j < 16; ++j) {
      int l = tid + 256*j;
      float kv = Kc[l];
#pragma unroll
      for (int i = 0; i < NCAND; ++i)
        acc[i] += Qs[(l + taus[i]) & 4095] * kv;
    }
  }
#pragma unroll
  for (int i = 0; i < NCAND; ++i) {
    float v = acc[i];
    for (int off = 32; off > 0; off >>= 1) v += __shfl_down(v, off);
    if ((tid & 63) == 0) red[(tid >> 6)*NCAND + i] = v;
  }
  __syncthreads();
  if (tid < NCAND) {
    float s = red[tid] + red[NCAND + tid] + red[2*NCAND + tid] + red[3*NCAND + tid];
    refpart[(size_t)(b*32 + chunk)*NCAND + tid] = s;
  }
}

__global__ void finalize_kernel(const float* __restrict__ refpart,
                                const int* __restrict__ flags,
                                float* __restrict__ cand_val)
{
  int b = blockIdx.x;
  if (!flags[b]) return;
  int i = threadIdx.x;
  if (i >= NCAND) return;
  double s = 0.0;
  for (int g = 0; g < 32; ++g) s += (double)refpart[(size_t)(b*32 + g)*NCAND + i];
  cand_val[b*NCAND + i] = (float)(s / 512.0);
}

// ---------------- select top-16 of 18, softmax ----------------
__global__ void probs_kernel(const float* __restrict__ cand_val,
                             const int* __restrict__ cand_idx,
                             float* __restrict__ probs, int* __restrict__ delays)
{
  int b = blockIdx.x;
  if (threadIdx.x != 0) return;
  float v[NCAND]; int ix[NCAND]; bool used[NCAND];
  for (int i = 0; i < NCAND; ++i) {
    v[i] = cand_val[b*NCAND + i]; ix[i] = cand_idx[b*NCAND + i]; used[i] = false;
  }
  float sel_v[KTOP]; int sel_i[KTOP];
  for (int k = 0; k < KTOP; ++k) {
    int best = -1;
    for (int i = 0; i < NCAND; ++i) {
      if (used[i]) continue;
      if (best < 0 || v[i] > v[best] || (v[i] == v[best] && ix[i] < ix[best])) best = i;
    }
    used[best] = true; sel_v[k] = v[best]; sel_i[k] = ix[best];
  }
  float mx = sel_v[0];
  for (int k = 1; k < KTOP; ++k) mx = fmaxf(mx, sel_v[k]);
  float e[KTOP]; float se = 0.f;
  for (int k = 0; k < KTOP; ++k) { e[k] = __expf(sel_v[k] - mx); se += e[k]; }
  for (int k = 0; k < KTOP; ++k) {
    probs[b*KTOP + k]  = e[k] / se;
    delays[b*KTOP + k] = sel_i[k];
  }
}

// ---------------- shift-aggregate ----------------
__global__ __launch_bounds__(256) void agg_kernel(
    const float* __restrict__ OV, const float* __restrict__ probs,
    const int* __restrict__ delays, float* __restrict__ out)
{
  int row = blockIdx.x * 2 + (threadIdx.x >> 7);
  int b = row >> 12;
  int l = row & 4095;
  int c4 = (threadIdx.x & 127) << 2;
  float p[KTOP]; int d[KTOP];
#pragma unroll
  for (int i = 0; i < KTOP; ++i) { p[i] = probs[b*KTOP + i]; d[i] = delays[b*KTOP + i]; }
  float4 acc = make_float4(0.f, 0.f, 0.f, 0.f);
#pragma unroll
  for (int i = 0; i < KTOP; ++i) {
    int ls = (l + d[i]) & 4095;
    float4 v = *reinterpret_cast<const float4*>(OV + ((size_t)(b*4096 + ls))*512 + c4);
    acc.x += p[i]*v.x; acc.y += p[i]*v.y; acc.z += p[i]*v.z; acc.w += p[i]*v.w;
  }
  *reinterpret_cast<float4*>(out + (size_t)row*512 + c4) = acc;
}

// ---------------- launch ----------------
extern "C" void kernel_launch(void* const* d_in, const int* in_sizes, int n_in,
                              void* d_out, int out_size, void* d_ws, size_t ws_size,
                              hipStream_t stream)
{
  const float* queries = (const float*)d_in[0];
  const float* keys    = (const float*)d_in[1];
  const float* values  = (const float*)d_in[2];
  const float* Wq = (const float*)d_in[3];
  const float* bq = (const float*)d_in[4];
  const float* Wk = (const float*)d_in[5];
  const float* bk = (const float*)d_in[6];
  const float* Wv = (const float*)d_in[7];
  const float* bv = (const float*)d_in[8];
  const float* Wo = (const float*)d_in[9];
  const float* bo = (const float*)d_in[10];

  char* ws = (char*)d_ws;
  size_t off = 0;
  float* Qt   = (float*)(ws + off);   off += (size_t)B_*E_*L_*4;       // 128 MB
  float2* Spart = (float2*)(ws + off); off += (size_t)B_*32*L_*8;      // 16.8 MB
  float* corr = (float*)(ws + off);   off += (size_t)B_*L_*4;          // 0.26 MB
  float* Wc   = (float*)(ws + off);   off += (size_t)E_*E_*4;          // 1 MB
  float* bc   = (float*)(ws + off);   off += (size_t)E_*4;
  float2* tw  = (float2*)(ws + off);  off += (size_t)2048*8;
  float* cand_val = (float*)(ws + off); off += (size_t)B_*NCAND*4;
  int*   cand_idx = (int*)(ws + off);   off += (size_t)B_*NCAND*4;
  int*   flags    = (int*)(ws + off);   off += (size_t)B_*4;
  float* probs    = (float*)(ws + off); off += (size_t)B_*KTOP*4;
  int*   delays   = (int*)(ws + off);   off += (size_t)B_*KTOP*4;
  float* refpart  = (float*)(ws + off); off += (size_t)B_*32*NCAND*4;
  // peak ws ~146.4 MB

  float* Kt = (float*)d_out;   // d_out doubles as K scratch until agg_kernel
  float* OV = Qt;              // OV reuses Q buffer (after fft + refine consume Qt)

  init_tw_kernel<<<8, 256, 0, stream>>>(tw);
  combine_kernel<<<E_, 256, 0, stream>>>(Wo, Wv, bv, bo, Wc, bc);
  gemm_mfma<true><<<dim3(512, 4), 256, 0, stream>>>(queries, Wq, bq, Qt);
  gemm_mfma<true><<<dim3(512, 4), 256, 0, stream>>>(keys,    Wk, bk, Kt);
  fft_corr_kernel<<<B_*32, 256, 0, stream>>>(Qt, Kt, tw, Spart);
  ifft_kernel<<<B_, 256, 0, stream>>>(Spart, tw, corr);
  topk_kernel<<<B_, 256, 0, stream>>>(corr, cand_val, cand_idx, flags);
  refine_kernel<<<B_*32, 256, 0, stream>>>(Qt, Kt, cand_idx, flags, refpart);
  finalize_kernel<<<B_, 32, 0, stream>>>(refpart, flags, cand_val);
  probs_kernel<<<B_, 64, 0, stream>>>(cand_val, cand_idx, probs, delays);
  gemm_mfma<false><<<dim3(512, 4), 256, 0, stream>>>(values, Wc, bc, OV);
  agg_kernel<<<B_*L_/2, 256, 0, stream>>>(OV, probs, delays, (float*)d_out);
}